// Round 11
// baseline (304.352 us; speedup 1.0000x reference)
//
#include <hip/hip_runtime.h>
#include <hip/hip_bf16.h>

#define NT 20000
#define NU 2000
#define HID 256
#define HEADS 8
#define FPH 32
#define E_TT 320000
#define E_UT 100000
#define CAP 80
#define NDEG 490

typedef __attribute__((ext_vector_type(2))) float f32x2;

__device__ inline unsigned char f2q(float f) {
  return (unsigned char)(__builtin_amdgcn_cvt_pk_fp8_f32(f, f, 0, false) & 0xff);
}

// =============== prep: combined-weight GEMMs + attn projections + deg count =========
// G[5][33][256]: m0: Ew_t@W0tt (+row32: eb@W0tt)          -> stage1-task
//                m1: Uw@W0ut   (+row32: ub@W0ut)          -> stage1-usv-combined
//                m2: P0@W1tt   (+row32: p0b@W1tt)         -> stage2
//                m3: P1@Dec    (+row32: p1b@Dec + dec_b)  -> stage3
//                m4: usv_enc_w (+row32: usv_enc_b)        -> stage1-usv-encoder
// P[6][33][8] slots: 0=Lel0 1=Mer0 2=Mer2 3=Lel2 4=Lel1 5=Mer1  (row32 = const)
__global__ __launch_bounds__(256) void prep(
    const float* __restrict__ task_enc_w, const float* __restrict__ task_enc_b,
    const float* __restrict__ usv_enc_w, const float* __restrict__ usv_enc_b,
    const float* __restrict__ l0_post_w, const float* __restrict__ l0_post_b,
    const float* __restrict__ l1_post_w, const float* __restrict__ l1_post_b,
    const float* __restrict__ l0_tt_wsrc, const float* __restrict__ l0_tt_wdst,
    const float* __restrict__ l0_tt_al, const float* __restrict__ l0_tt_ar,
    const float* __restrict__ l0_ut_wsrc, const float* __restrict__ l0_ut_wdst,
    const float* __restrict__ l0_ut_al, const float* __restrict__ l0_ut_ar,
    const float* __restrict__ l1_tt_wsrc, const float* __restrict__ l1_tt_wdst,
    const float* __restrict__ l1_tt_al, const float* __restrict__ l1_tt_ar,
    const float* __restrict__ task_dec_w, const float* __restrict__ task_dec_b,
    float* __restrict__ G, float* __restrict__ P,
    const int* __restrict__ tt_dst, const int* __restrict__ ut_dst,
    int* __restrict__ tt_deg, int* __restrict__ ut_deg) {
  int b = blockIdx.x, tid = threadIdx.x;
  if (b < 16) {
    // type A: combined G matrices. block = (mat m, row-group grp); grp3 adds bias row.
    __shared__ float Alds[9][256];
    int m = b >> 2, grp = b & 3;
    const float* Am = (m == 0) ? task_enc_w : (m == 1) ? usv_enc_w
                     : (m == 2) ? l0_post_w : l1_post_w;
    const float* bA = (m == 0) ? task_enc_b : (m == 1) ? usv_enc_b
                     : (m == 2) ? l0_post_b : l1_post_b;
    const float* Bm = (m == 0) ? l0_tt_wsrc : (m == 1) ? l0_ut_wsrc
                     : (m == 2) ? l1_tt_wsrc : task_dec_w;
    int nr = (grp == 3) ? 9 : 8;
#pragma unroll
    for (int j = 0; j < 9; ++j)
      if (j < nr) Alds[j][tid] = (j < 8) ? Am[(grp * 8 + j) * 256 + tid] : bA[tid];
    __syncthreads();
    float acc[9];
#pragma unroll
    for (int j = 0; j < 9; ++j) acc[j] = 0.f;
    for (int cp = 0; cp < 256; ++cp) {
      float bv = Bm[cp * 256 + tid];
#pragma unroll
      for (int j = 0; j < 9; ++j)
        if (j < nr) acc[j] += Alds[j][cp] * bv;
    }
    float* Gm = G + m * 33 * 256;
#pragma unroll
    for (int j = 0; j < 9; ++j) {
      if (j >= nr) continue;
      int k = (j == 8) ? 32 : grp * 8 + j;
      float v = acc[j];
      if (m == 3 && j == 8) v += task_dec_b[tid];
      Gm[k * 256 + tid] = v;
    }
  } else if (b < 22) {
    // type B: attn projections [33][8]
    __shared__ float w2s[256][8];
    int p = b - 16;
    const float* Ap; const float* bp; const float* Wd; const float* vv; int slot;
    switch (p) {
      case 0: Ap = task_enc_w; bp = task_enc_b; Wd = l0_tt_wdst; vv = l0_tt_ar; slot = 1; break;
      case 1: Ap = task_enc_w; bp = task_enc_b; Wd = l0_ut_wdst; vv = l0_ut_ar; slot = 2; break;
      case 2: Ap = l0_post_w;  bp = l0_post_b;  Wd = l1_tt_wdst; vv = l1_tt_ar; slot = 5; break;
      case 3: Ap = task_enc_w; bp = task_enc_b; Wd = l0_tt_wsrc; vv = l0_tt_al; slot = 0; break;
      case 4: Ap = usv_enc_w;  bp = usv_enc_b;  Wd = l0_ut_wsrc; vv = l0_ut_al; slot = 3; break;
      default: Ap = l0_post_w; bp = l0_post_b;  Wd = l1_tt_wsrc; vv = l1_tt_al; slot = 4; break;
    }
    for (int i = tid; i < 2048; i += 256) {
      int cp = i >> 3, h = i & 7;
      float s = 0.f;
#pragma unroll
      for (int f = 0; f < 32; ++f) s += Wd[cp * 256 + h * 32 + f] * vv[h * 32 + f];
      w2s[cp][h] = s;
    }
    __syncthreads();
    float* Pp = P + slot * 264;
    for (int idx = tid; idx < 264; idx += 256) {
      int k = idx >> 3, h = idx & 7;
      const float* src = (k < 32) ? Ap + k * 256 : bp;
      float s = 0.f;
      for (int cp = 0; cp < 256; ++cp) s += src[cp] * w2s[cp][h];
      Pp[idx] = s;
    }
  } else if (b == 22) {
    // type C: copy raw usv encoder into G m4
    float* G4 = G + 4 * 33 * 256;
    for (int i = tid; i < 33 * 256; i += 256)
      G4[i] = (i < 32 * 256) ? usv_enc_w[i] : usv_enc_b[i - 32 * 256];
  } else {
    // type D: degree count (grid-stride)
    int start = (b - 23) * 256 + tid, stride = NDEG * 256;
    for (int e = start; e < E_TT; e += stride) atomicAdd(&tt_deg[tt_dst[e]], 1);
    for (int e = start; e < E_UT; e += stride) atomicAdd(&ut_deg[ut_dst[e]], 1);
  }
}

// ---------------- CSR scan ----------------
__global__ __launch_bounds__(1024) void scan2(const int* __restrict__ d0, int* __restrict__ o0,
                                              int* __restrict__ c0,
                                              const int* __restrict__ d1, int* __restrict__ o1,
                                              int* __restrict__ c1, int n) {
  const int* deg = blockIdx.x ? d1 : d0;
  int* off = blockIdx.x ? o1 : o0;
  int* cursor = blockIdx.x ? c1 : c0;
  int tid = threadIdx.x;
  const int C = 20;
  int base = tid * C;
  int local[C];
  int s = 0;
#pragma unroll
  for (int i = 0; i < C; ++i) {
    int idx = base + i;
    int v = (idx < n) ? deg[idx] : 0;
    local[i] = s;
    s += v;
  }
  int lane = tid & 63, wave = tid >> 6;
  int x = s;
#pragma unroll
  for (int d = 1; d < 64; d <<= 1) {
    int y = __shfl_up(x, d, 64);
    if (lane >= d) x += y;
  }
  __shared__ int wsum[16];
  if (lane == 63) wsum[wave] = x;
  __syncthreads();
  if (wave == 0) {
    int wv = (lane < 16) ? wsum[lane] : 0;
#pragma unroll
    for (int d = 1; d < 16; d <<= 1) {
      int y = __shfl_up(wv, d, 64);
      if (lane >= d) wv += y;
    }
    if (lane < 16) wsum[lane] = wv;
  }
  __syncthreads();
  int waveoff = (wave == 0) ? 0 : wsum[wave - 1];
  int excl = waveoff + x - s;
#pragma unroll
  for (int i = 0; i < C; ++i) {
    int idx = base + i;
    if (idx < n) {
      int o = excl + local[i];
      off[idx] = o;
      cursor[idx] = o;
    }
  }
  if (tid == 1023) off[n] = waveoff + x;
}

// =============== stage body: [N,32] @ G[33][256] (+proj epilogues) ==================
__device__ inline void stage_body(float* lds,
                                  const float* __restrict__ in0,
                                  const float* __restrict__ in1,
                                  const float* __restrict__ Gm,
                                  const float* __restrict__ Pm, int nproj,
                                  float* __restrict__ e0, float* __restrict__ e1,
                                  float* __restrict__ e2,
                                  float* __restrict__ outF,
                                  unsigned char* __restrict__ outQ,
                                  int relu, float* __restrict__ gsum, int blk) {
  float* Ws = lds;                       // 33*256
  float* Pr = lds + 33 * 256;            // 3*264
  float* Ar = lds + 33 * 256 + 3 * 264;  // 16*32
  int tid = threadIdx.x;
  for (int i = tid; i < 33 * 256; i += 256) Ws[i] = Gm[i];
  for (int i = tid; i < nproj * 264; i += 256) Pr[i] = Pm[i];
  int n0 = blk * 16;
  for (int i = tid; i < 512; i += 256) {
    int r = i >> 5, k = i & 31;
    float v = in0[(size_t)(n0 + r) * 32 + k];
    if (in1) v += in1[(size_t)(n0 + r) * 32 + k];
    Ar[r * 32 + k] = v;
  }
  __syncthreads();
  float bb = Ws[32 * 256 + tid];
  float colacc = 0.f;
  for (int r = 0; r < 16; ++r) {
    float acc = bb;
#pragma unroll
    for (int k = 0; k < 32; ++k) acc += Ar[r * 32 + k] * Ws[k * 256 + tid];
    if (relu) acc = fmaxf(acc, 0.f);
    size_t o = (size_t)(n0 + r) * 256 + tid;
    if (outF) outF[o] = acc;
    if (outQ) outQ[o] = f2q(acc);
    colacc += acc;
  }
  if (gsum) atomicAdd(&gsum[tid], colacc);
  if (nproj && tid < 128) {
    int r = tid >> 3, h = tid & 7;
    for (int p = 0; p < nproj; ++p) {
      const float* Pp = Pr + p * 264;
      float s = Pp[32 * 8 + h];
#pragma unroll
      for (int k = 0; k < 32; ++k) s += Ar[r * 32 + k] * Pp[k * 8 + h];
      float* op = (p == 0) ? e0 : (p == 1) ? e1 : e2;
      op[(size_t)(n0 + r) * 8 + h] = s;
    }
  }
}

// stage1: scatter blocks + task stage + usv-combined stage + usv-encoder stage
__global__ __launch_bounds__(256) void stage1(
    const int* __restrict__ tt_src, const int* __restrict__ tt_dst,
    int* __restrict__ tt_cur, int* __restrict__ tt_srcs,
    const int* __restrict__ ut_src, const int* __restrict__ ut_dst,
    int* __restrict__ ut_cur, int* __restrict__ ut_srcs,
    const float* __restrict__ task_feat, const float* __restrict__ usv_feat,
    const float* __restrict__ G, const float* __restrict__ P,
    unsigned char* __restrict__ fs_q, float* __restrict__ el0,
    float* __restrict__ er0, float* __restrict__ er2,
    float* __restrict__ out_usv, unsigned char* __restrict__ fsu_q,
    float* __restrict__ el2, float* __restrict__ g,
    int nbE, int nbT, int nbU) {
  extern __shared__ float lds[];
  int b = blockIdx.x;
  if (b < nbE) {
    int e = b * 256 + (int)threadIdx.x;
    if (e < E_TT) {
      int p = atomicAdd(&tt_cur[tt_dst[e]], 1);
      tt_srcs[p] = tt_src[e];
    }
    int e2_ = e - E_TT;
    if (e2_ >= 0 && e2_ < E_UT) {
      int p = atomicAdd(&ut_cur[ut_dst[e2_]], 1);
      ut_srcs[p] = ut_src[e2_];
    }
    return;
  }
  b -= nbE;
  if (b < nbT) {
    stage_body(lds, task_feat, nullptr, G, P, 3, el0, er0, er2,
               nullptr, fs_q, 0, nullptr, b);
    return;
  }
  b -= nbT;
  if (b < nbU) {
    // combined: usv_feat @ m1 -> fsu_q (fp8), el2 projection
    stage_body(lds, usv_feat, nullptr, G + 33 * 256, P + 3 * 264, 1, el2, nullptr, nullptr,
               nullptr, fsu_q, 0, nullptr, b);
    return;
  }
  b -= nbU;
  // encoder: usv_feat @ m4 -> out_usv (f32) + colsum into g
  stage_body(lds, usv_feat, nullptr, G + 4 * 33 * 256, nullptr, 0, nullptr, nullptr, nullptr,
             out_usv, nullptr, 0, g, b);
}

// stage2: hm_t+hm_u -> fs_q(L1), el1, er1
__global__ __launch_bounds__(256) void stage_mid(const float* __restrict__ hm_t,
                                                 const float* __restrict__ hm_u,
                                                 const float* __restrict__ G,
                                                 const float* __restrict__ P,
                                                 unsigned char* __restrict__ fs_q,
                                                 float* __restrict__ el,
                                                 float* __restrict__ er) {
  extern __shared__ float lds[];
  stage_body(lds, hm_t, hm_u, G + 2 * 33 * 256, P + 4 * 264, 2, el, er, nullptr,
             nullptr, fs_q, 0, nullptr, blockIdx.x);
}

// stage3: hm1 -> out_task (relu, f32) + colsum
__global__ __launch_bounds__(256) void stage_out(const float* __restrict__ hm,
                                                 const float* __restrict__ G,
                                                 float* __restrict__ out_task,
                                                 float* __restrict__ g) {
  extern __shared__ float lds[];
  stage_body(lds, hm, nullptr, G + 3 * 33 * 256, nullptr, 0, nullptr, nullptr, nullptr,
             out_task, nullptr, 1, g, blockIdx.x);
}

// =============== fused softmax + aggregation + head-mean, fp8 gather ================
__device__ inline float gat_w(const float* __restrict__ el, int src, int h,
                              float ern, float mh) {
  float l = el[src * 8 + h] + ern;
  l = l >= 0.f ? l : 0.2f * l;
  return __expf(l - mh);
}

__device__ inline void gat_body(const int* __restrict__ offs, const int* __restrict__ srcs,
                                const float* __restrict__ el, const float* __restrict__ er,
                                const unsigned char* __restrict__ fsq,
                                const float* __restrict__ bias0,
                                const float* __restrict__ bias1,
                                float* __restrict__ hmOut, int n, float (*wl)[8]) {
  int lane = threadIdx.x & 63;
  int e0 = offs[n], e1 = offs[n + 1];
  float4 o;
  if (e0 == e1) {
    o = (float4){0.f, 0.f, 0.f, 0.f};
    if (bias0) {
      o = *(const float4*)(bias0 + lane * 4);
      if (bias1) {
        float4 b1 = *(const float4*)(bias1 + lane * 4);
        o.x += b1.x; o.y += b1.y; o.z += b1.z; o.w += b1.w;
      }
    }
  } else {
    int h1 = lane & 7, slot = lane >> 3;
    float ern1 = er[n * 8 + h1];
    float m = -3.4e38f;
    for (int i = e0 + slot; i < e1; i += 8) {
      float l = el[srcs[i] * 8 + h1] + ern1;
      l = l >= 0.f ? l : 0.2f * l;
      int idx = i - e0;
      if (idx < CAP) wl[idx][h1] = l;
      m = fmaxf(m, l);
    }
    m = fmaxf(m, __shfl_xor(m, 8));
    m = fmaxf(m, __shfl_xor(m, 16));
    m = fmaxf(m, __shfl_xor(m, 32));
    float s = 0.f;
    for (int i = e0 + slot; i < e1; i += 8) {
      int idx = i - e0;
      float l;
      if (idx < CAP) l = wl[idx][h1];
      else {
        l = el[srcs[i] * 8 + h1] + ern1;
        l = l >= 0.f ? l : 0.2f * l;
      }
      float w = __expf(l - m);
      if (idx < CAP) wl[idx][h1] = w;
      s += w;
    }
    s += __shfl_xor(s, 8);
    s += __shfl_xor(s, 16);
    s += __shfl_xor(s, 32);
    int h2 = lane >> 3;
    float mh = __shfl(m, h2);
    float sh = __shfl(s, h2);
    float ern2 = __shfl(ern1, h2);
    float ax = 0.f, ay = 0.f, az = 0.f, aw = 0.f;
    int i = e0;
    for (; i + 8 <= e1; i += 8) {
      int sj[8];
      unsigned qj[8];
#pragma unroll
      for (int j = 0; j < 8; ++j) sj[j] = srcs[i + j];
#pragma unroll
      for (int j = 0; j < 8; ++j)
        qj[j] = *(const unsigned*)(fsq + (size_t)sj[j] * 256 + lane * 4);
      int idx = i - e0;
      float wj[8];
      if (idx + 7 < CAP) {
#pragma unroll
        for (int j = 0; j < 8; ++j) wj[j] = wl[idx + j][h2];
      } else {
#pragma unroll
        for (int j = 0; j < 8; ++j)
          wj[j] = (idx + j < CAP) ? wl[idx + j][h2] : gat_w(el, sj[j], h2, ern2, mh);
      }
#pragma unroll
      for (int j = 0; j < 8; ++j) {
        f32x2 lo = __builtin_amdgcn_cvt_pk_f32_fp8(qj[j], false);
        f32x2 up = __builtin_amdgcn_cvt_pk_f32_fp8(qj[j], true);
        ax += wj[j] * lo[0];
        ay += wj[j] * lo[1];
        az += wj[j] * up[0];
        aw += wj[j] * up[1];
      }
    }
    for (; i < e1; ++i) {
      int src = srcs[i];
      int idx = i - e0;
      float w = (idx < CAP) ? wl[idx][h2] : gat_w(el, src, h2, ern2, mh);
      unsigned q = *(const unsigned*)(fsq + (size_t)src * 256 + lane * 4);
      f32x2 lo = __builtin_amdgcn_cvt_pk_f32_fp8(q, false);
      f32x2 up = __builtin_amdgcn_cvt_pk_f32_fp8(q, true);
      ax += w * lo[0];
      ay += w * lo[1];
      az += w * up[0];
      aw += w * up[1];
    }
    float sinv = 1.f / sh;
    o = (float4){ax * sinv, ay * sinv, az * sinv, aw * sinv};
    if (bias0) {
      float4 b = *(const float4*)(bias0 + lane * 4);
      o.x += b.x; o.y += b.y; o.z += b.z; o.w += b.w;
      if (bias1) {
        float4 b1 = *(const float4*)(bias1 + lane * 4);
        o.x += b1.x; o.y += b1.y; o.z += b1.z; o.w += b1.w;
      }
    }
  }
  // head-mean across the 8 head-groups
  o.x += __shfl_xor(o.x, 8); o.x += __shfl_xor(o.x, 16); o.x += __shfl_xor(o.x, 32);
  o.y += __shfl_xor(o.y, 8); o.y += __shfl_xor(o.y, 16); o.y += __shfl_xor(o.y, 32);
  o.z += __shfl_xor(o.z, 8); o.z += __shfl_xor(o.z, 16); o.z += __shfl_xor(o.z, 32);
  o.w += __shfl_xor(o.w, 8); o.w += __shfl_xor(o.w, 16); o.w += __shfl_xor(o.w, 32);
  if (lane < 8) {
    float4 hmv = {o.x * 0.125f, o.y * 0.125f, o.z * 0.125f, o.w * 0.125f};
    *(float4*)(hmOut + (size_t)n * 32 + lane * 4) = hmv;
  }
}

__global__ __launch_bounds__(256) void gat_fused2(
    const int* __restrict__ oA, const int* __restrict__ sA,
    const float* __restrict__ elA, const float* __restrict__ erA,
    const unsigned char* __restrict__ fA,
    const float* __restrict__ b0A, const float* __restrict__ b1A,
    float* __restrict__ hmA, int ndstA, int nA,
    const int* __restrict__ oB, const int* __restrict__ sB,
    const float* __restrict__ elB, const float* __restrict__ erB,
    const unsigned char* __restrict__ fB, float* __restrict__ hmB, int ndstB) {
  __shared__ float wlds[4][CAP][8];
  int wv = threadIdx.x >> 6;
  int b = blockIdx.x;
  if (b < nA) {
    int n = b * 4 + wv;
    if (n >= ndstA) return;
    gat_body(oA, sA, elA, erA, fA, b0A, b1A, hmA, n, wlds[wv]);
  } else {
    int n = (b - nA) * 4 + wv;
    if (n >= ndstB) return;
    gat_body(oB, sB, elB, erB, fB, nullptr, nullptr, hmB, n, wlds[wv]);
  }
}

// ---------------- global projection (with mean scaling) ----------------
__global__ __launch_bounds__(512) void global_proj(const float* __restrict__ g,
                                                   const float* __restrict__ W,
                                                   const float* __restrict__ b,
                                                   float* __restrict__ out) {
  __shared__ float gl[512];
  int tid = threadIdx.x;
  gl[tid] = g[tid] * (tid < 256 ? (1.f / NU) : (1.f / NT));
  __syncthreads();
  float s = b[tid];
  for (int k = 0; k < 512; ++k) s += gl[k] * W[k * 512 + tid];
  out[tid] = s;
}

extern "C" void kernel_launch(void* const* d_in, const int* in_sizes, int n_in,
                              void* d_out, int out_size, void* d_ws, size_t ws_size,
                              hipStream_t stream) {
  const float* usv_feat   = (const float*)d_in[0];
  const float* task_feat  = (const float*)d_in[1];
  const float* usv_enc_w  = (const float*)d_in[2];
  const float* usv_enc_b  = (const float*)d_in[3];
  const float* task_enc_w = (const float*)d_in[4];
  const float* task_enc_b = (const float*)d_in[5];
  const float* l0_tt_wsrc = (const float*)d_in[6];
  const float* l0_tt_wdst = (const float*)d_in[7];
  const float* l0_tt_al   = (const float*)d_in[8];
  const float* l0_tt_ar   = (const float*)d_in[9];
  const float* l0_tt_bias = (const float*)d_in[10];
  const float* l0_ut_wsrc = (const float*)d_in[11];
  const float* l0_ut_wdst = (const float*)d_in[12];
  const float* l0_ut_al   = (const float*)d_in[13];
  const float* l0_ut_ar   = (const float*)d_in[14];
  const float* l0_ut_bias = (const float*)d_in[15];
  const float* l0_post_w  = (const float*)d_in[16];
  const float* l0_post_b  = (const float*)d_in[17];
  const float* l1_tt_wsrc = (const float*)d_in[18];
  const float* l1_tt_wdst = (const float*)d_in[19];
  const float* l1_tt_al   = (const float*)d_in[20];
  const float* l1_tt_ar   = (const float*)d_in[21];
  const float* l1_tt_bias = (const float*)d_in[22];
  const float* l1_post_w  = (const float*)d_in[23];
  const float* l1_post_b  = (const float*)d_in[24];
  const float* task_dec_w = (const float*)d_in[25];
  const float* task_dec_b = (const float*)d_in[26];
  const float* gp_w       = (const float*)d_in[27];
  const float* gp_b       = (const float*)d_in[28];
  const int* tt_src = (const int*)d_in[29];
  const int* tt_dst = (const int*)d_in[30];
  const int* ut_src = (const int*)d_in[31];
  const int* ut_dst = (const int*)d_in[32];

  float* out = (float*)d_out;
  float* out_usv  = out;
  float* out_task = out + NU * HID;
  float* out_glob = out + NU * HID + NT * HID;

  char* ws = (char*)d_ws;
  size_t off = 0;
  auto alloc_f = [&](size_t n) {
    float* p = (float*)(ws + off);
    off += ((n * 4 + 1023) / 1024) * 1024;
    return p;
  };
  auto alloc_i = [&](size_t n) {
    int* p = (int*)(ws + off);
    off += ((n * 4 + 1023) / 1024) * 1024;
    return p;
  };
  auto alloc_b = [&](size_t n) {
    unsigned char* p = (unsigned char*)(ws + off);
    off += ((n + 1023) / 1024) * 1024;
    return p;
  };

  unsigned char* fs_q  = alloc_b((size_t)NT * HID);
  unsigned char* fsu_q = alloc_b((size_t)NU * HID);
  float* hm_t  = alloc_f((size_t)NT * FPH);
  float* hm_u  = alloc_f((size_t)NT * FPH);
  float* el    = alloc_f((size_t)NT * HEADS);
  float* er    = alloc_f((size_t)NT * HEADS);
  float* el2   = alloc_f((size_t)NU * HEADS);
  float* er2   = alloc_f((size_t)NT * HEADS);
  float* G     = alloc_f(5 * 33 * 256);
  float* P     = alloc_f(6 * 264);
  // zero-span: tt_deg, ut_deg, g contiguous
  size_t zero_base = off;
  int* tt_deg  = alloc_i(NT);
  int* ut_deg  = alloc_i(NT);
  float* g     = alloc_f(512);
  size_t zero_len = off - zero_base;
  int* tt_offs = alloc_i(NT + 1);
  int* tt_cur  = alloc_i(NT);
  int* tt_srcs = alloc_i(E_TT);
  int* ut_offs = alloc_i(NT + 1);
  int* ut_cur  = alloc_i(NT);
  int* ut_srcs = alloc_i(E_UT);

  // 1) zero deg + g
  hipMemsetAsync(tt_deg, 0, zero_len, stream);

  // 2) prep: combined weights + projections + m4 copy + degree count
  prep<<<23 + NDEG, 256, 0, stream>>>(
      task_enc_w, task_enc_b, usv_enc_w, usv_enc_b,
      l0_post_w, l0_post_b, l1_post_w, l1_post_b,
      l0_tt_wsrc, l0_tt_wdst, l0_tt_al, l0_tt_ar,
      l0_ut_wsrc, l0_ut_wdst, l0_ut_al, l0_ut_ar,
      l1_tt_wsrc, l1_tt_wdst, l1_tt_al, l1_tt_ar,
      task_dec_w, task_dec_b, G, P, tt_dst, ut_dst, tt_deg, ut_deg);

  // 3) CSR scan
  scan2<<<2, 1024, 0, stream>>>(tt_deg, tt_offs, tt_cur, ut_deg, ut_offs, ut_cur, NT);

  // 4) scatter + stage1 (task / usv-combined / usv-encoder)
  int nbE = (E_TT + E_UT + 255) / 256;
  int nbT = NT / 16, nbU = NU / 16;
  size_t LDSB = (size_t)(33 * 256 + 3 * 264 + 16 * 32) * 4;
  stage1<<<nbE + nbT + nbU + nbU, 256, LDSB, stream>>>(
      tt_src, tt_dst, tt_cur, tt_srcs, ut_src, ut_dst, ut_cur, ut_srcs,
      task_feat, usv_feat, G, P,
      fs_q, el, er, er2, out_usv, fsu_q, el2, g, nbE, nbT, nbU);

  int nbAgg = (NT + 3) / 4;

  // 5) layer 0 aggregation (tt -> hm_t with both biases, ut -> hm_u)
  gat_fused2<<<nbAgg + nbAgg, 256, 0, stream>>>(
      tt_offs, tt_srcs, el, er, fs_q, l0_tt_bias, l0_ut_bias, hm_t, NT, nbAgg,
      ut_offs, ut_srcs, el2, er2, fsu_q, hm_u, NT);

  // 6) stage2: (hm_t+hm_u) -> fs_q(L1), el1, er1
  stage_mid<<<nbT, 256, LDSB, stream>>>(hm_t, hm_u, G, P, fs_q, el, er);

  // 7) layer 1 aggregation -> hm_t
  gat_fused2<<<nbAgg, 256, 0, stream>>>(
      tt_offs, tt_srcs, el, er, fs_q, l1_tt_bias, nullptr, hm_t, NT, nbAgg,
      tt_offs, tt_srcs, el, er, fs_q, hm_u, 0);

  // 8) stage3: hm_t -> out_task (relu) + colsum
  stage_out<<<nbT, 256, LDSB, stream>>>(hm_t, G, out_task, g + 256);

  // 9) global projection
  global_proj<<<1, 512, 0, stream>>>(g, gp_w, gp_b, out_glob);
}